// Round 3
// baseline (101.667 us; speedup 1.0000x reference)
//
#include <hip/hip_runtime.h>
#include <math.h>

#define NPTS 8192
#define TCH 64          // tgt chunks
#define TILE 128        // tgt tile points (NPTS / TCH)
#define SCH 4           // src chunks
#define SPB 2048        // src points per block (NPTS / SCH)
#define NRED 128        // reduce blocks (32 per combo)

struct Xforms { float B[3][4]; float R[3][4]; float T[3][4]; };

__device__ __forceinline__ void compute_xforms(const float* __restrict__ quat,
                                               const float* __restrict__ bt,
                                               const float* __restrict__ anchor,
                                               const float* __restrict__ axis,
                                               const float* __restrict__ theta,
                                               Xforms& X) {
  float q0 = quat[0], q1 = quat[1], q2 = quat[2], q3 = quat[3];
  float n = sqrtf(q0 * q0 + q1 * q1 + q2 * q2 + q3 * q3);
  float a = q0 / n, b = q1 / n, c = q2 / n, d = q3 / n;
  X.B[0][0] = 1.f - 2.f * c * c - 2.f * d * d;
  X.B[0][1] = 2.f * b * c - 2.f * a * d;
  X.B[0][2] = 2.f * a * c + 2.f * b * d;
  X.B[0][3] = bt[0];
  X.B[1][0] = 2.f * b * c + 2.f * a * d;
  X.B[1][1] = 1.f - 2.f * b * b - 2.f * d * d;
  X.B[1][2] = 2.f * c * d - 2.f * a * b;
  X.B[1][3] = bt[1];
  X.B[2][0] = 2.f * b * d - 2.f * a * c;
  X.B[2][1] = 2.f * a * b + 2.f * c * d;
  X.B[2][2] = 1.f - 2.f * b * b - 2.f * c * c;
  X.B[2][3] = bt[2];

  float ax = anchor[0], ay = anchor[1], az = anchor[2];
  float u = axis[0], v = axis[1], w = axis[2];
  float th = theta[0];
  float cs = cosf(th), sn = sinf(th), oc = 1.f - cs;
  X.R[0][0] = u * u + (v * v + w * w) * cs;
  X.R[0][1] = u * v * oc - w * sn;
  X.R[0][2] = u * w * oc + v * sn;
  X.R[0][3] = (ax * (v * v + w * w) - u * (ay * v + az * w)) * oc + (ay * w - az * v) * sn;
  X.R[1][0] = u * v * oc + w * sn;
  X.R[1][1] = v * v + (u * u + w * w) * cs;
  X.R[1][2] = v * w * oc - u * sn;
  X.R[1][3] = (ay * (u * u + w * w) - v * (ax * u + az * w)) * oc + (az * u - ax * w) * sn;
  X.R[2][0] = u * w * oc - v * sn;
  X.R[2][1] = v * w * oc + u * sn;
  X.R[2][2] = w * w + (u * u + v * v) * cs;
  X.R[2][3] = (az * (u * u + v * v) - w * (ax * u + ay * v)) * oc + (ax * v - ay * u) * sn;

#pragma unroll
  for (int i = 0; i < 3; i++) {
#pragma unroll
    for (int j = 0; j < 4; j++) {
      float s = X.R[i][0] * X.B[0][j] + X.R[i][1] * X.B[1][j] + X.R[i][2] * X.B[2][j];
      if (j == 3) s += X.R[i][3];
      X.T[i][j] = s;
    }
  }
}

// grid (SCH=4, TCH=64, combos=4) = 1024 blocks, 256 threads.
// combo c: part=c>>1, dir=c&1. dir 0: src=Xform*cad, tgt=cam; dir 1: src=cam, tgt=Xform*cad.
// Each block: 8 src pts/thread in regs, 128-pt tgt tile in LDS, writes partial
// min-d^2 to a UNIQUE minpart slot (no atomics).
__global__ __launch_bounds__(256, 4) void chamfer_kernel(
    const float* __restrict__ cam, const float* __restrict__ cad,
    const float* __restrict__ quat, const float* __restrict__ bt,
    const float* __restrict__ anchor, const float* __restrict__ axis,
    const float* __restrict__ theta,
    float* __restrict__ minpart, float* __restrict__ sums,
    unsigned int* __restrict__ counter) {
  const int tid = threadIdx.x;
  if (blockIdx.x == 0 && blockIdx.y == 0 && blockIdx.z == 0) {
    if (tid < 4) sums[tid] = 0.f;
    if (tid == 4) *counter = 0u;
  }

  Xforms X;
  compute_xforms(quat, bt, anchor, axis, theta, X);

  const int combo = blockIdx.z;
  const int part = combo >> 1;
  const int dir = combo & 1;

  // per-element select keeps M in registers (no pointer-to-stack scratch)
  float M[3][4];
#pragma unroll
  for (int i = 0; i < 3; i++)
#pragma unroll
    for (int j = 0; j < 4; j++) M[i][j] = part ? X.T[i][j] : X.B[i][j];

  const float* __restrict__ srcraw = (dir ? cam : cad) + part * NPTS * 3;
  const float* __restrict__ tgtraw = (dir ? cad : cam) + part * NPTS * 3;
  const bool src_xf = (dir == 0);
  const bool tgt_xf = (dir == 1);

  const int sbase = blockIdx.x * SPB;

  float4 s[8];
  float vmin[8];
#pragma unroll
  for (int i = 0; i < 8; i++) {
    int idx = sbase + i * 256 + tid;
    float px = srcraw[idx * 3 + 0], py = srcraw[idx * 3 + 1], pz = srcraw[idx * 3 + 2];
    if (src_xf) {
      float qx = M[0][0] * px + M[0][1] * py + M[0][2] * pz + M[0][3];
      float qy = M[1][0] * px + M[1][1] * py + M[1][2] * pz + M[1][3];
      float qz = M[2][0] * px + M[2][1] * py + M[2][2] * pz + M[2][3];
      px = qx; py = qy; pz = qz;
    }
    s[i] = make_float4(px, py, pz, 0.5f * (px * px + py * py + pz * pz));
    vmin[i] = 3.4e38f;
  }

  __shared__ float4 tile[TILE];
  if (tid < TILE) {
    int idx = blockIdx.y * TILE + tid;
    float px = tgtraw[idx * 3 + 0], py = tgtraw[idx * 3 + 1], pz = tgtraw[idx * 3 + 2];
    if (tgt_xf) {
      float qx = M[0][0] * px + M[0][1] * py + M[0][2] * pz + M[0][3];
      float qy = M[1][0] * px + M[1][1] * py + M[1][2] * pz + M[1][3];
      float qz = M[2][0] * px + M[2][1] * py + M[2][2] * pz + M[2][3];
      px = qx; py = qy; pz = qz;
    }
    tile[tid] = make_float4(px, py, pz, 0.5f * (px * px + py * py + pz * pz));
  }
  __syncthreads();

  // min d^2 = 2*(s.w + min_k(t.w - s·t)) — 3 FMA + 1 min per pair
#pragma unroll 4
  for (int k = 0; k < TILE; k++) {
    float4 t = tile[k];  // same-address LDS read -> broadcast, conflict-free
#pragma unroll
    for (int i = 0; i < 8; i++) {
      float v = fmaf(-s[i].z, t.z, t.w);
      v = fmaf(-s[i].y, t.y, v);
      v = fmaf(-s[i].x, t.x, v);
      vmin[i] = fminf(vmin[i], v);
    }
  }

  float* __restrict__ slot = minpart + ((combo * TCH + blockIdx.y) << 13) + sbase;
#pragma unroll
  for (int i = 0; i < 8; i++) {
    slot[i * 256 + tid] = fmaxf(0.f, 2.f * (s[i].w + vmin[i]));
  }
}

// 128 blocks: 32 per combo, 256 pts each. Min over 64 chunks, sqrt, block-sum,
// atomicAdd; last-block-done finalizes all 35 outputs (device-scope, XCD-safe).
__global__ __launch_bounds__(256) void reduce_finalize_kernel(
    const float* __restrict__ minpart, float* __restrict__ sums,
    unsigned int* __restrict__ counter,
    const float* __restrict__ pw,
    const float* __restrict__ quat, const float* __restrict__ bt,
    const float* __restrict__ anchor, const float* __restrict__ axis,
    const float* __restrict__ theta, float* __restrict__ out) {
  const int tid = threadIdx.x;
  const int combo = blockIdx.x >> 5;
  const int pt = (blockIdx.x & 31) * 256 + tid;
  const float* __restrict__ mp = minpart + combo * TCH * NPTS + pt;

  float m0 = 3.4e38f, m1 = 3.4e38f, m2 = 3.4e38f, m3 = 3.4e38f;
#pragma unroll
  for (int c = 0; c < TCH; c += 4) {
    m0 = fminf(m0, mp[(c + 0) * NPTS]);
    m1 = fminf(m1, mp[(c + 1) * NPTS]);
    m2 = fminf(m2, mp[(c + 2) * NPTS]);
    m3 = fminf(m3, mp[(c + 3) * NPTS]);
  }
  float ssum = sqrtf(fminf(fminf(m0, m1), fminf(m2, m3)));

#pragma unroll
  for (int off = 32; off > 0; off >>= 1) ssum += __shfl_down(ssum, off);
  __shared__ float part[4];
  if ((tid & 63) == 0) part[tid >> 6] = ssum;
  __syncthreads();

  if (tid == 0) {
    float blocksum = part[0] + part[1] + part[2] + part[3];
    atomicAdd(&sums[combo], blocksum);
    __threadfence();
    unsigned int old = atomicAdd(counter, 1u);
    if (old == NRED - 1) {
      __threadfence();
      float s0 = __hip_atomic_load(&sums[0], __ATOMIC_ACQUIRE, __HIP_MEMORY_SCOPE_AGENT);
      float s1 = __hip_atomic_load(&sums[1], __ATOMIC_ACQUIRE, __HIP_MEMORY_SCOPE_AGENT);
      float s2 = __hip_atomic_load(&sums[2], __ATOMIC_ACQUIRE, __HIP_MEMORY_SCOPE_AGENT);
      float s3 = __hip_atomic_load(&sums[3], __ATOMIC_ACQUIRE, __HIP_MEMORY_SCOPE_AGENT);
      Xforms X;
      compute_xforms(quat, bt, anchor, axis, theta, X);
      const float inv = 1.0f / (float)NPTS;
      float base_obj = (s0 + s1) * inv;
      float child_obj = (s2 + s3) * inv;
      out[0] = (pw[0] * base_obj + pw[1] * child_obj) * 0.5f;
      out[1] = base_obj;
      out[2] = child_obj;
      for (int i = 0; i < 3; i++)
        for (int j = 0; j < 4; j++) out[3 + i * 4 + j] = X.B[i][j];
      out[15] = 0.f; out[16] = 0.f; out[17] = 0.f; out[18] = 1.f;
      for (int i = 0; i < 3; i++)
        for (int j = 0; j < 4; j++) out[19 + i * 4 + j] = X.R[i][j];
      out[31] = 0.f; out[32] = 0.f; out[33] = 0.f; out[34] = 1.f;
    }
  }
}

extern "C" void kernel_launch(void* const* d_in, const int* in_sizes, int n_in,
                              void* d_out, int out_size, void* d_ws, size_t ws_size,
                              hipStream_t stream) {
  const float* cam  = (const float*)d_in[0];  // [2,8192,3]
  const float* cad  = (const float*)d_in[1];  // [2,8192,3]
  const float* xyz  = (const float*)d_in[2];  // [1,3] anchor
  const float* rpy  = (const float*)d_in[3];  // [1,3] axis
  const float* pw   = (const float*)d_in[4];  // [2]
  const float* quat = (const float*)d_in[5];  // [4]
  const float* bt   = (const float*)d_in[6];  // [3,1]
  const float* js   = (const float*)d_in[7];  // [1]

  // ws layout: minpart [4][64][8192] f32 = 8 MB | sums 16 B | counter 4 B
  float* minpart = (float*)d_ws;
  float* sums = (float*)((char*)d_ws + (size_t)4 * TCH * NPTS * sizeof(float));
  unsigned int* counter = (unsigned int*)(sums + 4);
  float* out = (float*)d_out;

  hipLaunchKernelGGL(chamfer_kernel, dim3(SCH, TCH, 4), dim3(256), 0, stream,
                     cam, cad, quat, bt, xyz, rpy, js, minpart, sums, counter);
  hipLaunchKernelGGL(reduce_finalize_kernel, dim3(NRED), dim3(256), 0, stream,
                     minpart, sums, counter, pw, quat, bt, xyz, rpy, js, out);
}